// Round 1
// baseline (1328.931 us; speedup 1.0000x reference)
//
#include <hip/hip_runtime.h>
#include <hip/hip_bf16.h>

#define Bsz 2048
#define Tlen 512
#define Hdim 256
#define Vocab 64

typedef __attribute__((ext_vector_type(8))) __bf16 bf16x8;
typedef __attribute__((ext_vector_type(4))) float float4v;

__device__ inline unsigned short f32_bf16(float f) {
    unsigned int u = __float_as_uint(f);
    u += 0x7FFF + ((u >> 16) & 1);   // round-to-nearest-even
    return (unsigned short)(u >> 16);
}

// Barrier with LDS-only drain: ds ops must be visible across waves, but the
// deferred global stores need NO ordering (out is never read). Avoids the
// vmcnt(0) HBM-store drain __syncthreads() would insert every step.
__device__ inline void barrier_lds() {
    asm volatile("s_waitcnt lgkmcnt(0)\n\ts_barrier" ::: "memory");
}

// Build B-operand fragments for the recurrent matmul, K extended to 320:
//   k in [0,256):  B[k][o] = Wh[o][k] = W[o*512 + 256 + k]
//   k in [256,320): B[k][o] = P[k-256][o] = sum_h emb[v][h]*W[o*512+h] + b[o]
// Fragment layout (16x16x32 bf16 B-operand): lane L supplies
//   B[k = ks*32 + (L>>4)*8 + j][o = w*64 + nt*16 + (L&15)], j=0..7 contiguous.
// Linear storage: idx = ((((w*4+nt)*10 + ks)*64 + lane)*8 + j
__global__ void build_frags(const float* __restrict__ emb,
                            const float* __restrict__ W,
                            const float* __restrict__ bias,
                            unsigned short* __restrict__ wt) {
    int idx = blockIdx.x * 256 + threadIdx.x;   // 0..81919
    int j    = idx & 7;
    int lane = (idx >> 3) & 63;
    int fi   = idx >> 9;                        // 0..159
    int ks   = fi % 10;
    int wnt  = fi / 10;                         // 0..15
    int o = (wnt >> 2) * 64 + (wnt & 3) * 16 + (lane & 15);
    int k = ks * 32 + ((lane >> 4) & 3) * 8 + j;
    float val;
    if (k < Hdim) {
        val = W[o * (2 * Hdim) + Hdim + k];
    } else {
        int v = k - Hdim;
        float s = bias[o];
        for (int h = 0; h < Hdim; ++h)
            s += emb[v * Hdim + h] * W[o * (2 * Hdim) + h];
        val = s;
    }
    wt[idx] = f32_bf16(val);
}

// One block = 8 batch rows, full 512-step recurrence, no inter-block sync.
// 4 waves; wave w owns output slice o in [w*64, w*64+64).
// B fragments register-resident (160 VGPR/lane). h exchanged via LDS (bf16),
// double-buffered, one lgkm-only barrier per step. Global stores deferred one
// step and never drained inside the loop.
// Epilogue dedup: C rows 8..15 duplicate rows 0..7 (A-row padding), so lane
// groups split the epilogue: lg in {0,1} -> nt {0,1}; lg in {2,3} -> nt {2,3}.
// Each lane processes 8 values instead of 16; stores run with all 64 lanes.
__global__ __launch_bounds__(256, 1) void rnn_main(
        const int* __restrict__ tokens,
        const float* __restrict__ h0,
        const unsigned short* __restrict__ wt,
        float* __restrict__ out) {
    __shared__ int tok_lds[8 * 513];                 // stride 513: conflict-free
    __shared__ unsigned short hb[2][8 * 264];        // stride 264: 2-way max (free)

    const int tid  = threadIdx.x;
    const int lane = tid & 63;
    const int w    = tid >> 6;          // wave 0..3
    const int lm   = lane & 15;         // A: m index / C: col index
    const int lg   = lane >> 4;         // lane group 0..3
    const int b_base = blockIdx.x * 8;
    const int o_base = w * 64;

    // epilogue-dedup assignments (per-lane, NOT wave-uniform)
    const int np   = (lg >> 1) * 2;     // nt-pair base: 0 or 2
    const int srow = (lg & 1) * 4;      // row base: 0 or 4

    // stage tokens for our 8 rows (coalesced)
    for (int e = 0; e < 16; ++e) {
        int idx = e * 256 + tid;        // 0..4095
        int m = idx >> 9, t = idx & 511;
        tok_lds[m * 513 + t] = tokens[(b_base + m) * Tlen + t];
    }
    // stage h0 -> hb[0] as bf16
    for (int e = 0; e < 8; ++e) {
        int idx = e * 256 + tid;        // 0..2047
        int m = idx >> 8, c = idx & 255;
        hb[0][m * 264 + c] = f32_bf16(h0[(b_base + m) * Hdim + c]);
    }

    // load register-resident B fragments (one-time, coalesced b128)
    bf16x8 bfr[4][10];
    const bf16x8* wp = (const bf16x8*)wt;
#pragma unroll
    for (int nt = 0; nt < 4; ++nt)
#pragma unroll
        for (int ks = 0; ks < 10; ++ks)
            bfr[nt][ks] = wp[(((w * 4 + nt) * 10 + ks) * 64) + lane];

    float pv[2][4];   // previous step's sigmoid outputs (deferred store)

#pragma unroll 2
    for (int t = 0; t < Tlen; ++t) {
        const int cur = t & 1;
        const int nxt = cur ^ 1;
        barrier_lds();     // hb[cur] ready; prior epoch's LDS reads complete

        // issue LDS reads first so their latency overlaps the store issue
        int tok = tok_lds[(lm & 7) * 513 + t];
        bf16x8 a[10];
        const unsigned short* hrow = &hb[cur][(lm & 7) * 264];
#pragma unroll
        for (int ks = 0; ks < 8; ++ks)
            a[ks] = *(const bf16x8*)(hrow + ks * 32 + lg * 8);

        // deferred global store of step t-1 (all 64 lanes, 8 dwords each)
        if (t > 0) {
#pragma unroll
            for (int i = 0; i < 2; ++i)
#pragma unroll
                for (int r = 0; r < 4; ++r) {
                    long off = ((long)(t - 1) * Bsz + (b_base + srow + r)) * Hdim;
                    out[off + o_base + (np + i) * 16 + lm] = pv[i][r];
                }
        }

        // one-hot K-extension selects P[tok] inside the MFMA
        {
            bf16x8 a8, a9;
#pragma unroll
            for (int j = 0; j < 8; ++j) {
                int v0 = lg * 8 + j;
                a8[j] = (v0 == tok)      ? (__bf16)1.0f : (__bf16)0.0f;
                a9[j] = (v0 + 32 == tok) ? (__bf16)1.0f : (__bf16)0.0f;
            }
            a[8] = a8;
            a[9] = a9;
        }

        // 4 independent accumulator chains, ks-outer for ILP
        float4v acc[4];
#pragma unroll
        for (int nt = 0; nt < 4; ++nt) {
            float4v z = {0.f, 0.f, 0.f, 0.f};
            acc[nt] = z;
        }
#pragma unroll
        for (int ks = 0; ks < 10; ++ks)
#pragma unroll
            for (int nt = 0; nt < 4; ++nt)
                acc[nt] = __builtin_amdgcn_mfma_f32_16x16x32_bf16(
                    a[ks], bfr[nt][ks], acc[nt], 0, 0, 0);

        // epilogue (dedup): per-lane select of the two relevant accumulators.
        // Static indices only (runtime-indexed ext_vector arrays -> scratch).
        float4v accA = (lg >= 2) ? acc[2] : acc[0];
        float4v accB = (lg >= 2) ? acc[3] : acc[1];

#pragma unroll
        for (int r = 0; r < 4; ++r) {
            float sA = 1.0f / (1.0f + __expf(-accA[r]));
            float sB = 1.0f / (1.0f + __expf(-accB[r]));
            pv[0][r] = sA;
            pv[1][r] = sB;
            int row = srow + r;
            hb[nxt][row * 264 + o_base + (np + 0) * 16 + lm] = f32_bf16(sA);
            hb[nxt][row * 264 + o_base + (np + 1) * 16 + lm] = f32_bf16(sB);
        }
    }

    // tail: store step T-1
#pragma unroll
    for (int i = 0; i < 2; ++i)
#pragma unroll
        for (int r = 0; r < 4; ++r) {
            long off = ((long)(Tlen - 1) * Bsz + (b_base + srow + r)) * Hdim;
            out[off + o_base + (np + i) * 16 + lm] = pv[i][r];
        }
}

extern "C" void kernel_launch(void* const* d_in, const int* in_sizes, int n_in,
                              void* d_out, int out_size, void* d_ws, size_t ws_size,
                              hipStream_t stream) {
    const int*   tokens = (const int*)d_in[0];
    const float* h0     = (const float*)d_in[1];
    const float* emb    = (const float*)d_in[2];
    const float* W      = (const float*)d_in[3];
    const float* b      = (const float*)d_in[4];
    unsigned short* wt  = (unsigned short*)d_ws;   // 81920 bf16 = 160 KB

    build_frags<<<320, 256, 0, stream>>>(emb, W, b, wt);
    rnn_main<<<256, 256, 0, stream>>>(tokens, h0, wt, (float*)d_out);
}

// Round 2
// 1217.899 us; speedup vs baseline: 1.0912x; 1.0912x over previous
//
#include <hip/hip_runtime.h>
#include <hip/hip_bf16.h>

#define Bsz 2048
#define Tlen 512
#define Hdim 256
#define Vocab 64

typedef __attribute__((ext_vector_type(8))) __bf16 bf16x8;
typedef __attribute__((ext_vector_type(4))) float float4v;

__device__ inline unsigned short f32_bf16(float f) {
    unsigned int u = __float_as_uint(f);
    u += 0x7FFF + ((u >> 16) & 1);   // round-to-nearest-even
    return (unsigned short)(u >> 16);
}

// Barrier with LDS-only drain: ds ops must be visible across waves, but the
// deferred global stores need NO ordering (out is never read). Avoids the
// vmcnt(0) HBM-store drain __syncthreads() would insert every step.
__device__ inline void barrier_lds() {
    asm volatile("s_waitcnt lgkmcnt(0)\n\ts_barrier" ::: "memory");
}

// Build B-operand fragments for the recurrent matmul, K extended to 320:
//   k in [0,256):  B[k][o] = Wh[o][k] = W[o*512 + 256 + k]
//   k in [256,320): B[k][o] = P[k-256][o] = sum_h emb[v][h]*W[o*512+h] + b[o]
// Fragment layout (16x16x32 bf16 B-operand): lane L supplies
//   B[k = ks*32 + (L>>4)*8 + j][o = 16*g + (L&15)], j=0..7 contiguous,
// where g = 16-col block index 0..15 (o block = 16*g).
// Linear storage: idx = (((g*10 + ks)*64 + lane)*8 + j
__global__ void build_frags(const float* __restrict__ emb,
                            const float* __restrict__ W,
                            const float* __restrict__ bias,
                            unsigned short* __restrict__ wt) {
    int idx = blockIdx.x * 256 + threadIdx.x;   // 0..81919
    int j    = idx & 7;
    int lane = (idx >> 3) & 63;
    int fi   = idx >> 9;                        // 0..159
    int ks   = fi % 10;
    int g    = fi / 10;                         // 0..15
    int o = g * 16 + (lane & 15);
    int k = ks * 32 + ((lane >> 4) & 3) * 8 + j;
    float val;
    if (k < Hdim) {
        val = W[o * (2 * Hdim) + Hdim + k];
    } else {
        int v = k - Hdim;
        float s = bias[o];
        for (int h = 0; h < Hdim; ++h)
            s += emb[v * Hdim + h] * W[o * (2 * Hdim) + h];
        val = s;
    }
    wt[idx] = f32_bf16(val);
}

// One block = 8 batch rows, full 512-step recurrence, no inter-block sync.
// 8 waves (512 threads) = 2 waves/SIMD for latency hiding; wave w owns output
// slice o in [w*32, w*32+32) (2 MFMA col-tiles). B fragments register-resident
// (80 VGPR/lane). h exchanged via LDS (bf16), double-buffered, one lgkm-only
// barrier per step.
// Chain shortening: the one-hot xproj MFMAs (ks 8,9) depend only on tokens and
// are computed BEFORE the barrier; the h-dependent MFMAs run as 4 independent
// chains of 4 (even/odd ks split x 2 col-tiles).
// Epilogue dedup: C rows 8..15 duplicate rows 0..7 (A-row padding), so lane
// groups split the work: lg&1 picks row half, lg>>1 picks which col-tile.
__global__ __launch_bounds__(512, 2) void rnn_main(
        const int* __restrict__ tokens,
        const float* __restrict__ h0,
        const unsigned short* __restrict__ wt,
        float* __restrict__ out) {
    __shared__ int tok_lds[8 * 513];                 // stride 513: conflict-free
    __shared__ unsigned short hb[2][8 * 264];        // stride 264

    const int tid  = threadIdx.x;
    const int lane = tid & 63;
    const int w    = tid >> 6;          // wave 0..7
    const int lm   = lane & 15;         // A: m index / C: col index
    const int lg   = lane >> 4;         // lane group 0..3
    const int b_base = blockIdx.x * 8;
    const int o_base = w * 32;

    // epilogue-dedup assignments (per-lane, NOT wave-uniform)
    const int sel  = lg >> 1;           // which col-tile this lane finalizes
    const int srow = (lg & 1) * 4;      // row base: 0 or 4

    // stage tokens for our 8 rows (coalesced)
    for (int e = 0; e < 8; ++e) {
        int idx = e * 512 + tid;        // 0..4095
        int m = idx >> 9, t = idx & 511;
        tok_lds[m * 513 + t] = tokens[(b_base + m) * Tlen + t];
    }
    // stage h0 -> hb[0] as bf16
    for (int e = 0; e < 4; ++e) {
        int idx = e * 512 + tid;        // 0..2047
        int m = idx >> 8, c = idx & 255;
        hb[0][m * 264 + c] = f32_bf16(h0[(b_base + m) * Hdim + c]);
    }

    // load register-resident B fragments (one-time, coalesced b128)
    bf16x8 bfr[2][10];
    const bf16x8* wp = (const bf16x8*)wt;
#pragma unroll
    for (int nt = 0; nt < 2; ++nt)
#pragma unroll
        for (int ks = 0; ks < 10; ++ks)
            bfr[nt][ks] = wp[(((w * 2 + nt) * 10 + ks) * 64) + lane];

    __syncthreads();   // staging visible before first pre-barrier token read

    float pv[4];       // previous step's sigmoid outputs (deferred store)
    float* op = out + (long)(b_base + srow) * Hdim + o_base + sel * 16 + lm;
    const long SS = (long)Bsz * Hdim;   // step stride in floats

#pragma unroll 2
    for (int t = 0; t < Tlen; ++t) {
        const int cur = t & 1;
        const int nxt = cur ^ 1;

        // ---- pre-barrier: xproj via one-hot K-extension (token-only dep) ----
        int tok = tok_lds[(lm & 7) * 513 + t];
        bf16x8 a8, a9;
#pragma unroll
        for (int j = 0; j < 8; ++j) {
            int v0 = lg * 8 + j;
            a8[j] = (v0 == tok)      ? (__bf16)1.0f : (__bf16)0.0f;
            a9[j] = (v0 + 32 == tok) ? (__bf16)1.0f : (__bf16)0.0f;
        }
        float4v ax[2];
#pragma unroll
        for (int nt = 0; nt < 2; ++nt) {
            float4v z = {0.f, 0.f, 0.f, 0.f};
            ax[nt] = __builtin_amdgcn_mfma_f32_16x16x32_bf16(
                a8, bfr[nt][8], z, 0, 0, 0);
            ax[nt] = __builtin_amdgcn_mfma_f32_16x16x32_bf16(
                a9, bfr[nt][9], ax[nt], 0, 0, 0);
        }

        barrier_lds();     // hb[cur] ready; prior epoch's LDS reads complete

        // A fragments from LDS (rows 8..15 are padding: alias rows 0..7)
        bf16x8 a[8];
        const unsigned short* hrow = &hb[cur][(lm & 7) * 264];
#pragma unroll
        for (int ks = 0; ks < 8; ++ks)
            a[ks] = *(const bf16x8*)(hrow + ks * 32 + lg * 8);

        // deferred global store of step t-1 (all 64 lanes, 4 dwords each)
        if (t > 0) {
#pragma unroll
            for (int r = 0; r < 4; ++r)
                op[(long)r * Hdim] = pv[r];
            op += SS;
        }

        // h-dependent MFMAs: 4 independent chains of depth 4
        float4v accE[2], accO[2];
#pragma unroll
        for (int nt = 0; nt < 2; ++nt) {
            accE[nt] = ax[nt];
            float4v z = {0.f, 0.f, 0.f, 0.f};
            accO[nt] = z;
        }
#pragma unroll
        for (int kp = 0; kp < 4; ++kp) {
#pragma unroll
            for (int nt = 0; nt < 2; ++nt)
                accE[nt] = __builtin_amdgcn_mfma_f32_16x16x32_bf16(
                    a[2 * kp], bfr[nt][2 * kp], accE[nt], 0, 0, 0);
#pragma unroll
            for (int nt = 0; nt < 2; ++nt)
                accO[nt] = __builtin_amdgcn_mfma_f32_16x16x32_bf16(
                    a[2 * kp + 1], bfr[nt][2 * kp + 1], accO[nt], 0, 0, 0);
        }

        // epilogue (dedup): per-lane select of this lane's col-tile.
        // Static indices only (runtime-indexed ext_vector arrays -> scratch).
        float4v aE = sel ? accE[1] : accE[0];
        float4v aO = sel ? accO[1] : accO[0];

        unsigned short* hw = &hb[nxt][srow * 264 + o_base + sel * 16 + lm];
#pragma unroll
        for (int r = 0; r < 4; ++r) {
            float x = aE[r] + aO[r];
            float e = __expf(-x);
            float s = __builtin_amdgcn_rcpf(1.0f + e);   // ~1ulp; bf16 path dominates error
            pv[r] = s;
            hw[r * 264] = f32_bf16(s);
        }
    }

    // tail: store step T-1
#pragma unroll
    for (int r = 0; r < 4; ++r)
        op[(long)r * Hdim] = pv[r];
}

extern "C" void kernel_launch(void* const* d_in, const int* in_sizes, int n_in,
                              void* d_out, int out_size, void* d_ws, size_t ws_size,
                              hipStream_t stream) {
    const int*   tokens = (const int*)d_in[0];
    const float* h0     = (const float*)d_in[1];
    const float* emb    = (const float*)d_in[2];
    const float* W      = (const float*)d_in[3];
    const float* b      = (const float*)d_in[4];
    unsigned short* wt  = (unsigned short*)d_ws;   // 81920 bf16 = 160 KB

    build_frags<<<320, 256, 0, stream>>>(emb, W, b, wt);
    rnn_main<<<256, 512, 0, stream>>>(tokens, h0, wt, (float*)d_out);
}